// Round 7
// baseline (402.832 us; speedup 1.0000x reference)
//
#include <hip/hip_runtime.h>
#include <hip/hip_bf16.h>

typedef unsigned short u16;
typedef unsigned int u32;
typedef __attribute__((ext_vector_type(8))) __bf16 bf16x8;
typedef __attribute__((ext_vector_type(4))) __bf16 bf16x4;
typedef __attribute__((ext_vector_type(4))) short short4v;
typedef __attribute__((ext_vector_type(4))) float f32x4;
typedef __attribute__((ext_vector_type(16))) float f32x16;

#define N_TOK 4096
#define DIMF  514
#define KPAD  544      // 17*32, zero-padded K for QKV gemm
#define OUT3  768
#define OUTD  256
#define RDIM  512
#define DIMP  640      // 5*128, zero-padded Wo output-dim for proj staging
#define FDIM  1542
#define SHIFT 16.0f
#define NCHUNK 2       // split-K chunks over the 4096 keys
#define KTILES ((N_TOK / NCHUNK) / 16)   // 128 16-key tiles per chunk
#define TILE_U16 8192                    // 16 KB tile: 8 K-frags + 8 V-regions

__device__ __forceinline__ bf16x8 ld_frag(const u16* p) {
    return __builtin_bit_cast(bf16x8, *reinterpret_cast<const uint4*>(p));
}
__device__ __forceinline__ u16 f2bf(float x) {
    return __builtin_bit_cast(u16, __float2bfloat16(x));
}
__device__ __forceinline__ float bf2f(u16 u) {
    return __bfloat162float(__builtin_bit_cast(__hip_bfloat16, u));
}
__device__ __forceinline__ f32x16 mfma_b(bf16x8 a, bf16x8 b, f32x16 c) {
    return __builtin_amdgcn_mfma_f32_32x32x16_bf16(a, b, c, 0, 0, 0);
}
__device__ __forceinline__ f32x4 mfma16(bf16x8 a, bf16x8 b, f32x4 c) {
    return __builtin_amdgcn_mfma_f32_16x16x32_bf16(a, b, c, 0, 0, 0);
}
// 16x16x16 bf16 MFMA with builtin-name fallback chain (instruction exists on
// gfx950 per ISA doc; only the clang builtin spelling is uncertain).
__device__ __forceinline__ f32x4 mfma16k16(bf16x4 a, bf16x4 b, f32x4 c) {
#if __has_builtin(__builtin_amdgcn_mfma_f32_16x16x16_bf16)
    return __builtin_amdgcn_mfma_f32_16x16x16_bf16(a, b, c, 0, 0, 0);
#elif __has_builtin(__builtin_amdgcn_mfma_f32_16x16x16bf16_1k)
    return __builtin_amdgcn_mfma_f32_16x16x16bf16_1k(
        __builtin_bit_cast(short4v, a), __builtin_bit_cast(short4v, b), c, 0, 0, 0);
#else
    asm volatile("v_mfma_f32_16x16x16_bf16 %0, %1, %2, %0"
                 : "+v"(c) : "v"(a), "v"(b));
    return c;
#endif
}
// async 16B/lane global -> LDS (LDS dest = wave-uniform base + lane*16)
__device__ __forceinline__ void gl_lds16(const u16* g, u16* l) {
    __builtin_amdgcn_global_load_lds(
        (const __attribute__((address_space(1))) void*)(g),
        (__attribute__((address_space(3))) void*)(l), 16, 0, 0);
}

// ---------------------------------------------------------------- prep
__global__ void prep_kernel(const float* __restrict__ t1, const float* __restrict__ t2,
                            const float* __restrict__ t1c,
                            const float* __restrict__ W1, const float* __restrict__ W2,
                            const float* __restrict__ W3,
                            const float* __restrict__ Wo1, const float* __restrict__ Wo2,
                            const float* __restrict__ Wo3,
                            u16* __restrict__ tA, u16* __restrict__ WqkvT,
                            u16* __restrict__ WoT)
{
    int idx = blockIdx.x * blockDim.x + threadIdx.x;
    const int TA_N = 3 * N_TOK * KPAD;
    const int WQ_N = 3 * OUT3 * KPAD;
    const int WO_N = 3 * DIMP * RDIM;
    if (idx < TA_N) {
        int m = idx / (N_TOK * KPAD);
        int rem = idx - m * (N_TOK * KPAD);
        int row = rem / KPAD;
        int col = rem - row * KPAD;
        const float* t = (m == 0) ? t1 : (m == 1) ? t2 : t1c;
        tA[idx] = (col < DIMF) ? f2bf(t[row * DIMF + col]) : (u16)0;
    } else if (idx < TA_N + WQ_N) {
        int i = idx - TA_N;
        int m = i / (OUT3 * KPAD);
        int rem = i - m * (OUT3 * KPAD);
        int n = rem / KPAD;
        int c = rem - n * KPAD;
        const float* W = (m == 0) ? W1 : (m == 1) ? W2 : W3;
        WqkvT[i] = (c < DIMF) ? f2bf(W[c * OUT3 + n]) : (u16)0;
    } else if (idx < TA_N + WQ_N + WO_N) {
        int i = idx - TA_N - WQ_N;
        int m = i / (DIMP * RDIM);
        int rem = i - m * (DIMP * RDIM);
        int n = rem / RDIM;
        int c = rem - n * RDIM;
        const float* W = (m == 0) ? Wo1 : (m == 1) ? Wo2 : Wo3;
        WoT[i] = (n < DIMF) ? f2bf(W[c * DIMF + n]) : (u16)0;
    }
}

// ---------------------------------------------------------------- QKV gemm
// R5: fragment-order global_load_lds staging, double buffer, 1 barrier/K-step.
__global__ __launch_bounds__(256, 2) void qkv_gemm(
    const u16* __restrict__ tA, const u16* __restrict__ WqkvT,
    const float* __restrict__ b1, const float* __restrict__ b2, const float* __restrict__ b3,
    u16* __restrict__ qbuf, u16* __restrict__ kbuf, u16* __restrict__ vT)
{
    const int mt = blockIdx.x, nt = blockIdx.y, mod = blockIdx.z;
    const u16* A = tA + mod * (N_TOK * KPAD);
    const u16* B = WqkvT + mod * (OUT3 * KPAD);
    const float* bias = (mod == 0) ? b1 : (mod == 1) ? b2 : b3;

    __shared__ alignas(16) u16 Fbuf[2][16 * 512];

    const int tid = threadIdx.x;
    const int lane = tid & 63;
    const int w = tid >> 6;
    const int wm = w & 1, wn = w >> 1;
    const int l31 = lane & 31, h = lane >> 5;

    auto stage = [&](int kt, u16* dst) {
#pragma unroll
        for (int fi = 0; fi < 4; fi++) {
            int f = w * 4 + fi;
            int rb = (f & 7) >> 1, kc = f & 1;
            const u16* src = (f < 8)
                ? &A[(mt * 128 + rb * 32 + l31) * KPAD + kt * 32 + kc * 16 + h * 8]
                : &B[(nt * 128 + rb * 32 + l31) * KPAD + kt * 32 + kc * 16 + h * 8];
            gl_lds16(src, dst + f * 512);
        }
    };

    f32x16 acc[2][2];
#pragma unroll
    for (int i = 0; i < 2; i++)
#pragma unroll
        for (int j = 0; j < 2; j++)
#pragma unroll
            for (int r = 0; r < 16; r++) acc[i][j][r] = 0.f;

    stage(0, Fbuf[0]);
    __syncthreads();   // tile 0 resident

    for (int kt = 0; kt < KPAD / 32; kt++) {
        const int p = kt & 1;
        if (kt + 1 < KPAD / 32) stage(kt + 1, Fbuf[p ^ 1]);
        const u16* FB = Fbuf[p];
#pragma unroll
        for (int kc = 0; kc < 2; kc++) {
            bf16x8 af[2], bfr[2];
#pragma unroll
            for (int mr = 0; mr < 2; mr++)
                af[mr] = ld_frag(&FB[((wm * 2 + mr) * 2 + kc) * 512 + lane * 8]);
#pragma unroll
            for (int nr = 0; nr < 2; nr++)
                bfr[nr] = ld_frag(&FB[(8 + (wn * 2 + nr) * 2 + kc) * 512 + lane * 8]);
#pragma unroll
            for (int mr = 0; mr < 2; mr++)
#pragma unroll
                for (int nr = 0; nr < 2; nr++)
                    acc[mr][nr] = mfma_b(af[mr], bfr[nr], acc[mr][nr]);
        }
        __syncthreads();
    }

    u16* qb = qbuf + mod * (N_TOK * OUTD);
    u16* kb = kbuf + mod * (N_TOK * OUTD);
    u16* vb = vT + mod * (OUTD * N_TOK);
#pragma unroll
    for (int mr = 0; mr < 2; mr++)
#pragma unroll
        for (int nr = 0; nr < 2; nr++)
#pragma unroll
            for (int r = 0; r < 16; r++) {
                int row = mt * 128 + wm * 64 + mr * 32 + (r & 3) + 8 * (r >> 2) + 4 * h;
                int col = nt * 128 + wn * 64 + nr * 32 + l31;
                u16 bv = f2bf(acc[mr][nr][r] + bias[col]);
                int cs = col >> 8, cc = col & 255;
                if (cs == 0)      qb[row * OUTD + cc] = bv;
                else if (cs == 1) kb[row * OUTD + cc] = bv;
                else              vb[cc * N_TOK + row] = bv;   // v transposed
            }
}

// ---------------------------------------------------------------- attention
// R7: 16 q-rows per wave -> occupancy unlock.
// Rationale: attn MFMA work = 103 GFLOP = 43 us pipe-minimum; measured
// pipe-busy 43.5 us at MfmaUtil 30% -> all remaining time is pipe-idle at
// the 2-waves/SIMD register wall (Oacc 128 = 32q x 256d / 64 lanes).
// Halving the per-wave q-tile halves the accumulator: Oacc 64 (16x f32x4 via
// 16x16x16 PV), qf 32 (8 frags) -> ~150 regs -> 3 waves/SIMD.
// S stays fully per-wave (16-key tiles, 8x 16x16x32, d contracted in-wave;
// no R3-style cross-wave exchange). With K=16 PV the S output layout
// (q=l&15, k=sg*4+r) IS the PV B-operand layout: no permlane repack at all.
// LDS: 16 KB/tile (8 K-frags + 8 V-regions, 16B/lane gl_lds16), 2-deep =
// 32 KB/block -> 3 blocks/CU (96 KB). NCHUNK=2 -> grid 64x6x2 = 768 =
// exactly 3x256: zero tail; Opart/combine traffic halves.
// V PV-reads are ds_read_b64 with <=4-way bank aliasing (1.58x on a small
// term) - accepted; staging must be 16B/lane (gl_lds has no 8B width).
__global__ __launch_bounds__(256, 3) void attn_kernel(
    const u16* __restrict__ qbuf, const u16* __restrict__ kbuf,
    const u16* __restrict__ vT, u16* __restrict__ Opart, float* __restrict__ lpart)
{
    const int qt = blockIdx.x;   // 0..63  (64-row q tile)
    const int g  = blockIdx.y;   // 0..5
    const int c  = blockIdx.z;   // 0..NCHUNK-1
    const int kv = g >> 1;
    const int mn = (kv == 0) ? 1 : 0;
    const int mx = (kv == 2) ? 1 : 2;
    const int qm = (g & 1) ? mx : mn;

    const u16* Qg = qbuf + qm * (N_TOK * OUTD);
    const u16* Kg = kbuf + kv * (N_TOK * OUTD);
    const u16* Vg = vT + kv * (OUTD * N_TOK);
    u16* Op = Opart + ((size_t)(c * 6 + g) * N_TOK + qt * 64) * OUTD;
    float* lp = lpart + (c * 6 + g) * N_TOK + qt * 64;

    __shared__ alignas(16) u16 Fbuf[2][TILE_U16];

    const int tid = threadIdx.x;
    const int lane = tid & 63;
    const int w = tid >> 6;           // 0..3
    const int sl = lane & 15, sg = lane >> 4;   // 16-lane group coords
    const int l31 = lane & 31, h = lane >> 5;
    const int q0 = qt * 64 + w * 16;

    // ---- stage 16-key tile at k0 (16 gl_lds16 ops, 4 per wave):
    // K frag j (j=0..7): lane l -> K[k0 + (l&15)][j*32 + (l>>4)*8 .. +8]
    //   (16x16x32 A-operand, read later at lane*16B: conflict-free)
    // V region sv (0..7): lane l -> V^T[sv*32 + (l&31)][k0 + (l>>5)*8 .. +8]
    //   (covers 32 d x 16 k; PV b64 reads pick 4-key pieces out of it)
    auto stage = [&](int k0, u16* dst) {
        if (w < 2) {
#pragma unroll
            for (int fi = 0; fi < 4; fi++) {
                int j = w * 4 + fi;
                gl_lds16(&Kg[(k0 + sl) * OUTD + j * 32 + sg * 8], dst + j * 512);
            }
        } else {
#pragma unroll
            for (int fi = 0; fi < 4; fi++) {
                int sv = (w - 2) * 4 + fi;
                gl_lds16(&Vg[(sv * 32 + l31) * N_TOK + k0 + h * 8],
                         dst + (8 + sv) * 512);
            }
        }
    };

    const int k0base = c * (N_TOK / NCHUNK);

    // prologue: stage tile 0; Q frags (16x16x32 B-operand):
    // qf[j]: lane l holds Q[q0 + (l&15)][j*32 + (l>>4)*8 .. +8]
    stage(k0base, Fbuf[0]);

    bf16x8 qf[8];
#pragma unroll
    for (int j = 0; j < 8; j++)
        qf[j] = ld_frag(&Qg[(q0 + sl) * OUTD + j * 32 + sg * 8]);

    f32x4 Oacc[16];
#pragma unroll
    for (int nb = 0; nb < 16; nb++)
#pragma unroll
        for (int r = 0; r < 4; r++) Oacc[nb][r] = 0.f;
    float lsum = 0.f;

    __syncthreads();   // drains vmcnt: tile 0 resident

    for (int kt = 0; kt < KTILES; kt++) {
        const int p = kt & 1;
        if (kt + 1 < KTILES) stage(k0base + (kt + 1) * 16, Fbuf[p ^ 1]);
        const u16* FB = Fbuf[p];

        // S = K_tile . Q^T  (16k x 16q), two independent 4-chains over d
        f32x4 Sa, Sb;
#pragma unroll
        for (int r = 0; r < 4; r++) { Sa[r] = 0.f; Sb[r] = 0.f; }
        __builtin_amdgcn_s_setprio(1);
#pragma unroll
        for (int j = 0; j < 4; j++) {
            bf16x8 kfa = ld_frag(&FB[j * 512 + lane * 8]);
            bf16x8 kfb = ld_frag(&FB[(4 + j) * 512 + lane * 8]);
            Sa = mfma16(kfa, qf[j], Sa);
            Sb = mfma16(kfb, qf[4 + j], Sb);
        }
        __builtin_amdgcn_s_setprio(0);

        // P = exp(S - 16): lane holds keys sg*4+0..3 for q = l&15 — this is
        // already the 16x16x16 B-operand layout. Pack in-lane to bf16x4.
        float e0 = __expf(Sa[0] + Sb[0] - SHIFT);
        float e1 = __expf(Sa[1] + Sb[1] - SHIFT);
        float e2 = __expf(Sa[2] + Sb[2] - SHIFT);
        float e3 = __expf(Sa[3] + Sb[3] - SHIFT);
        lsum += (e0 + e1) + (e2 + e3);
        uint2 pbu;
        pbu.x = (u32)f2bf(e0) | ((u32)f2bf(e1) << 16);
        pbu.y = (u32)f2bf(e2) | ((u32)f2bf(e3) << 16);
        bf16x4 pb = __builtin_bit_cast(bf16x4, pbu);

        // O^T[d][q] += V^T[d][k] P[k][q]: 16 independent 16x16x16 MFMAs.
        // V b64 read for chunk nb: (d = nb*16 + sl, keys sg*4..+3) staged at
        // region nb>>1, lane (d&31) + 32*(sg>>1), halfword offset (sg&1)*4.
        __builtin_amdgcn_s_setprio(1);
#pragma unroll
        for (int nb = 0; nb < 16; nb++) {
            int voff = (8 + (nb >> 1)) * 512
                     + ((nb & 1) * 16 + sl + 32 * (sg >> 1)) * 8 + (sg & 1) * 4;
            bf16x4 vf = __builtin_bit_cast(bf16x4,
                *reinterpret_cast<const uint2*>(&FB[voff]));
            Oacc[nb] = mfma16k16(vf, pb, Oacc[nb]);
        }
        __builtin_amdgcn_s_setprio(0);
        __syncthreads();   // waves done with FB; tile kt+1 loads drained
    }

    // l partials: lane's lsum covers keys of its sg-group for q = l&15;
    // reduce across the 4 sg-groups, lanes 0-15 hold q 0-15.
    lsum += __shfl_xor(lsum, 16, 64);
    lsum += __shfl_xor(lsum, 32, 64);
    if (lane < 16) lp[w * 16 + lane] = lsum;

    // transpose O^T -> [q][d] via wave-private LDS scratch (16x17 f32/wave).
    // Oacc[nb][r] = O[d = nb*16 + sg*4 + r][q = sl].
    float* Tb = reinterpret_cast<float*>(&Fbuf[0][0]) + w * (16 * 17);
#pragma unroll
    for (int nb = 0; nb < 16; nb++) {
#pragma unroll
        for (int r = 0; r < 4; r++)
            Tb[(sg * 4 + r) * 17 + sl] = Oacc[nb][r];
        __builtin_amdgcn_s_waitcnt(0);  // lgkm drain before re-read (wave-private)
        int qq = lane >> 2, d4 = (lane & 3) * 4;
        float v0 = Tb[(d4 + 0) * 17 + qq];
        float v1 = Tb[(d4 + 1) * 17 + qq];
        float v2 = Tb[(d4 + 2) * 17 + qq];
        float v3 = Tb[(d4 + 3) * 17 + qq];
        uint2 sv;
        sv.x = (u32)f2bf(v0) | ((u32)f2bf(v1) << 16);
        sv.y = (u32)f2bf(v2) | ((u32)f2bf(v3) << 16);
        *reinterpret_cast<uint2*>(&Op[(w * 16 + qq) * OUTD + nb * 16 + d4]) = sv;
        __builtin_amdgcn_s_waitcnt(0);
    }
}

// ---------------------------------------------------------------- combine
// o = sum(O_c)/sum(l_c) + k_residual -> rbuf bf16 [qm][q][slot*256+d]
__global__ __launch_bounds__(256, 1) void combine_kernel(
    const u16* __restrict__ Opart, const float* __restrict__ lpart,
    const u16* __restrict__ kbuf, u16* __restrict__ rbuf)
{
    const int q = blockIdx.x;
    const int g = blockIdx.y;
    const int d = threadIdx.x;
    const int kv = g >> 1;
    const int mn = (kv == 0) ? 1 : 0;
    const int mx = (kv == 2) ? 1 : 2;
    const int qm = (g & 1) ? mx : mn;
    const int sm = (qm == 0) ? 1 : 0;
    const int slot = (kv == sm) ? 0 : 1;

    float o = 0.f, l = 0.f;
#pragma unroll
    for (int c = 0; c < NCHUNK; c++) {
        o += bf2f(Opart[((size_t)(c * 6 + g) * N_TOK + q) * OUTD + d]);
        l += lpart[(c * 6 + g) * N_TOK + q];
    }
    float res = o / l + bf2f(kbuf[qm * (N_TOK * OUTD) + q * OUTD + d]);
    rbuf[qm * (size_t)(N_TOK * RDIM) + q * RDIM + slot * OUTD + d] = f2bf(res);
}

// ---------------------------------------------------------------- out proj
// R5: fragment-order gl_lds staging; B = WoT padded to DIMP=640 rows.
__global__ __launch_bounds__(256, 2) void proj_gemm(
    const u16* __restrict__ rbuf, const u16* __restrict__ WoT,
    const float* __restrict__ bo1, const float* __restrict__ bo2, const float* __restrict__ bo3,
    const float* __restrict__ t1, const float* __restrict__ t2, const float* __restrict__ t1c,
    float* __restrict__ feat)
{
    const int mt = blockIdx.x, nt = blockIdx.y, mod = blockIdx.z;
    const u16* A = rbuf + mod * (N_TOK * RDIM);
    const u16* B = WoT + mod * (DIMP * RDIM);
    const float* bias = (mod == 0) ? bo1 : (mod == 1) ? bo2 : bo3;
    const float* tres = (mod == 0) ? t1 : (mod == 1) ? t2 : t1c;

    __shared__ alignas(16) u16 Fbuf[2][16 * 512];

    const int tid = threadIdx.x;
    const int lane = tid & 63;
    const int w = tid >> 6;
    const int wm = w & 1, wn = w >> 1;
    const int l31 = lane & 31, h = lane >> 5;

    auto stage = [&](int kt, u16* dst) {
#pragma unroll
        for (int fi = 0; fi < 4; fi++) {
            int f = w * 4 + fi;
            int rb = (f & 7) >> 1, kc = f & 1;
            const u16* src = (f < 8)
                ? &A[(mt * 128 + rb * 32 + l31) * RDIM + kt * 32 + kc * 16 + h * 8]
                : &B[(nt * 128 + rb * 32 + l31) * RDIM + kt * 32 + kc * 16 + h * 8];
            gl_lds16(src, dst + f * 512);
        }
    };

    f32x16 acc[2][2];
#pragma unroll
    for (int i = 0; i < 2; i++)
#pragma unroll
        for (int j = 0; j < 2; j++)
#pragma unroll
            for (int r = 0; r < 16; r++) acc[i][j][r] = 0.f;

    stage(0, Fbuf[0]);
    __syncthreads();

    for (int kt = 0; kt < RDIM / 32; kt++) {
        const int p = kt & 1;
        if (kt + 1 < RDIM / 32) stage(kt + 1, Fbuf[p ^ 1]);
        const u16* FB = Fbuf[p];
#pragma unroll
        for (int kc = 0; kc < 2; kc++) {
            bf16x8 af[2], bfr[2];
#pragma unroll
            for (int mr = 0; mr < 2; mr++)
                af[mr] = ld_frag(&FB[((wm * 2 + mr) * 2 + kc) * 512 + lane * 8]);
#pragma unroll
            for (int nr = 0; nr < 2; nr++)
                bfr[nr] = ld_frag(&FB[(8 + (wn * 2 + nr) * 2 + kc) * 512 + lane * 8]);
#pragma unroll
            for (int mr = 0; mr < 2; mr++)
#pragma unroll
                for (int nr = 0; nr < 2; nr++)
                    acc[mr][nr] = mfma_b(af[mr], bfr[nr], acc[mr][nr]);
        }
        __syncthreads();
    }

#pragma unroll
    for (int mr = 0; mr < 2; mr++)
#pragma unroll
        for (int nr = 0; nr < 2; nr++)
#pragma unroll
            for (int r = 0; r < 16; r++) {
                int row = mt * 128 + wm * 64 + mr * 32 + (r & 3) + 8 * (r >> 2) + 4 * h;
                int col = nt * 128 + wn * 64 + nr * 32 + l31;
                if (col < DIMF) {
                    float v = acc[mr][nr][r] + bias[col] + tres[row * DIMF + col];
                    feat[row * FDIM + mod * DIMF + col] = v;
                }
            }
}

// ---------------------------------------------------------------- LN + head
__global__ __launch_bounds__(256, 1) void ln_head(
    const float* __restrict__ feat, const float* __restrict__ gam,
    const float* __restrict__ bet, const float* __restrict__ Wh,
    const float* __restrict__ bh, float* __restrict__ out)
{
    const int row = blockIdx.x;
    const float* x = feat + row * FDIM;
    const int tid = threadIdx.x;
    float v[7];
    float s = 0.f, ss = 0.f;
#pragma unroll
    for (int i = 0; i < 7; i++) {
        int idx = tid + i * 256;
        float val = (idx < FDIM) ? x[idx] : 0.f;
        v[i] = val; s += val; ss += val * val;
    }
#pragma unroll
    for (int m = 1; m < 64; m <<= 1) { s += __shfl_xor(s, m, 64); ss += __shfl_xor(ss, m, 64); }
    __shared__ float red[8];
    const int w = tid >> 6, lane = tid & 63;
    if (lane == 0) { red[w] = s; red[4 + w] = ss; }
    __syncthreads();
    s = red[0] + red[1] + red[2] + red[3];
    ss = red[4] + red[5] + red[6] + red[7];
    const float mu = s / (float)FDIM;
    const float var = ss / (float)FDIM - mu * mu;
    const float rstd = rsqrtf(var + 1e-5f);
    float a0 = 0.f, a1 = 0.f;
#pragma unroll
    for (int i = 0; i < 7; i++) {
        int idx = tid + i * 256;
        if (idx < FDIM) {
            float nv = (v[i] - mu) * rstd * gam[idx] + bet[idx];
            a0 += nv * Wh[idx * 2];
            a1 += nv * Wh[idx * 2 + 1];
        }
    }
#pragma unroll
    for (int m = 1; m < 64; m <<= 1) { a0 += __shfl_xor(a0, m, 64); a1 += __shfl_xor(a1, m, 64); }
    __shared__ float red2[8];
    if (lane == 0) { red2[w] = a0; red2[4 + w] = a1; }
    __syncthreads();
    if (tid == 0) {
        out[row * 2 + 0] = red2[0] + red2[1] + red2[2] + red2[3] + bh[0];
        out[row * 2 + 1] = red2[4] + red2[5] + red2[6] + red2[7] + bh[1];
    }
}

// ---------------------------------------------------------------- launch
extern "C" void kernel_launch(void* const* d_in, const int* in_sizes, int n_in,
                              void* d_out, int out_size, void* d_ws, size_t ws_size,
                              hipStream_t stream)
{
    const float* t1    = (const float*)d_in[0];
    const float* t2    = (const float*)d_in[1];
    const float* t1c   = (const float*)d_in[2];
    const float* Wqkv1 = (const float*)d_in[3];
    const float* bqkv1 = (const float*)d_in[4];
    const float* Wqkv2 = (const float*)d_in[5];
    const float* bqkv2 = (const float*)d_in[6];
    const float* Wqkv3 = (const float*)d_in[7];
    const float* bqkv3 = (const float*)d_in[8];
    const float* Wo1   = (const float*)d_in[9];
    const float* bo1   = (const float*)d_in[10];
    const float* Wo2   = (const float*)d_in[11];
    const float* bo2   = (const float*)d_in[12];
    const float* Wo3   = (const float*)d_in[13];
    const float* bo3   = (const float*)d_in[14];
    const float* ln_g  = (const float*)d_in[15];
    const float* ln_b  = (const float*)d_in[16];
    const float* Wh    = (const float*)d_in[17];
    const float* bh    = (const float*)d_in[18];

    char* ws = (char*)d_ws;
    size_t off = 0;
    u16* tA    = (u16*)(ws + off); off += (size_t)3 * N_TOK * KPAD * 2;
    u16* WqkvT = (u16*)(ws + off); off += (size_t)3 * OUT3 * KPAD * 2;
    u16* WoT   = (u16*)(ws + off); off += (size_t)3 * DIMP * RDIM * 2;
    u16* qbuf  = (u16*)(ws + off); off += (size_t)3 * N_TOK * OUTD * 2;
    u16* kbuf  = (u16*)(ws + off); off += (size_t)3 * N_TOK * OUTD * 2;
    u16* vT    = (u16*)(ws + off); off += (size_t)3 * OUTD * N_TOK * 2;
    u16* rbuf  = (u16*)(ws + off); off += (size_t)3 * N_TOK * RDIM * 2;
    u16* Opart = (u16*)(ws + off); off += (size_t)NCHUNK * 6 * N_TOK * OUTD * 2;
    float* lpart = (float*)(ws + off); off += (size_t)NCHUNK * 6 * N_TOK * 4;

    float* out  = (float*)d_out;
    float* feat = out + N_TOK * 2;

    const int prep_total = 3 * N_TOK * KPAD + 3 * OUT3 * KPAD + 3 * DIMP * RDIM;
    prep_kernel<<<(prep_total + 255) / 256, 256, 0, stream>>>(
        t1, t2, t1c, Wqkv1, Wqkv2, Wqkv3, Wo1, Wo2, Wo3, tA, WqkvT, WoT);

    qkv_gemm<<<dim3(32, 6, 3), 256, 0, stream>>>(
        tA, WqkvT, bqkv1, bqkv2, bqkv3, qbuf, kbuf, vT);

    attn_kernel<<<dim3(64, 6, NCHUNK), 256, 0, stream>>>(qbuf, kbuf, vT, Opart, lpart);

    combine_kernel<<<dim3(N_TOK, 6), 256, 0, stream>>>(Opart, lpart, kbuf, rbuf);

    proj_gemm<<<dim3(32, 5, 3), 256, 0, stream>>>(
        rbuf, WoT, bo1, bo2, bo3, t1, t2, t1c, feat);

    ln_head<<<4096, 256, 0, stream>>>(feat, ln_g, ln_b, Wh, bh, out);
}